// Round 8
// baseline (2861.556 us; speedup 1.0000x reference)
//
#include <hip/hip_runtime.h>

typedef unsigned short u16;
typedef unsigned int u32;
typedef unsigned long long u64;
typedef short bf16x8 __attribute__((ext_vector_type(8)));
typedef float f32x4 __attribute__((ext_vector_type(4)));

#define Bq 1024
#define Tq 256
#define Dq 128
#define Hq 512
#define GH 2048
#define Zq 64
#define NROW 16            // batch slices (rows)
#define NCOL 32            // h-col blocks per row
#define MBr 64             // batch rows per block

// workspace layout (bytes)
#define XP_OFF   0ull                      // x packed [T][B][D] bf16  : 67108864 B
#define WP_OFF   (XP_OFF + 67108864ull)    // W/U packed frags 32*81920: 2621440 B
#define HB_OFF   (WP_OFF + 2621440ull)     // h double buffer 2*[B][H] : 2097152 B
#define CT_OFF   (HB_OFF + 2097152ull)     // probe tokens + flags: 40960 B

#define POLL_CAP 65536                     // watchdog: never hang, fail loud

__device__ __forceinline__ u16 f2bf(float f){
  unsigned int u = __builtin_bit_cast(unsigned int, f);
  u += 0x7fffu + ((u >> 16) & 1u);          // RNE; inputs finite
  return (u16)(u >> 16);
}
__device__ __forceinline__ float bf2f(u16 v){
  unsigned int u = ((unsigned int)v) << 16;
  return __builtin_bit_cast(float, u);
}
__device__ __forceinline__ float sigmf_(float x){
  return 1.0f / (1.0f + __expf(-x));
}
__device__ __forceinline__ float softplusf_(float x){
  float r = __logf(1.0f + __expf(x));
  return (x > 20.0f) ? x : r;               // guard overflow: softplus(x)->x
}

// agent-coherent 16B load (sc1 path, reads coherence point) -- slow mode
__device__ __forceinline__ bf16x8 ld_h16_agent(const u16* p){
  union { u64 q[2]; bf16x8 v; } u;
  const u64* q = (const u64*)p;
  u.q[0] = __hip_atomic_load(q,     __ATOMIC_RELAXED, __HIP_MEMORY_SCOPE_AGENT);
  u.q[1] = __hip_atomic_load(q + 1, __ATOMIC_RELAXED, __HIP_MEMORY_SCOPE_AGENT);
  return u.v;
}
__device__ __forceinline__ void inv_l1(){
  asm volatile("buffer_inv sc0" ::: "memory");   // L1-only invalidate
}
// agent barrier pieces (PROVEN in R0; used for the one-time probe only).
// SYNC PROTOCOL LEDGER (hard-won):
//   R2: HIP workgroup-scope atomics as cross-block barrier -> arrivals
//       invisible, watchdog every step. NEVER downgrade the scope.
//   R4: per-wave arrivals (128 RMWs/step) -> RMW serialization ~100cy
//       each tripled the step cost. NEVER increase arrival count.
//   R5: inline-asm no-sc1 atomic at "local L2" -> container death.
//       NEVER replace the sc1 primitive itself.
//   R6: per-block monotonic FLAG STORES + wave-parallel gather: WORKS.
//   R7: anti-phase stagger: NULL -> throughput-bound (LDS/L2/VALU),
//       not phase-locked-stall-bound. Removed.
// PLACEMENT MODEL (fits R0 pass + R1 fail): pair-granular dispatch,
// XCD = (bx>>1)&7, CU pair = (2k,2k+1). R1's fail rules out XCD=bx&7.
// R8: map the CU pair to SAME ROW, adjacent j -> both blocks read the
// identical h-tile/x-slice through the shared L1 (phase-locked by the
// same barrier => temporal locality => L1 dedup of the L2 term).
__device__ __forceinline__ u32 bar_arrive(u32* c){
  return __hip_atomic_fetch_add(c, 1u, __ATOMIC_RELAXED, __HIP_MEMORY_SCOPE_AGENT);
}
__device__ __forceinline__ void bar_poll(u32* c, u32 target){
  for (int w = 0; w < POLL_CAP; ++w){
    if (__hip_atomic_load(c, __ATOMIC_RELAXED, __HIP_MEMORY_SCOPE_AGENT) >= target) break;
    __builtin_amdgcn_s_sleep(1);
  }
}
__device__ __forceinline__ void agent_bar(u32* c, u32 target){
  u32 old = bar_arrive(c);
  if (old + 1u >= target) return;            // last arriver: no poll
  bar_poll(c, target);
}

// ---- pack x [B,T,D] fp32 -> [T,B,D] bf16 -------------------------------
__global__ __launch_bounds__(256) void pack_x_k(const float4* __restrict__ x,
                                                ushort4* __restrict__ xp){
  int idx = blockIdx.x * 256 + threadIdx.x;          // 8,388,608 float4s
  int t = idx >> 15, rem = idx & 32767, b = rem >> 5, d4 = rem & 31;
  float4 v = x[(size_t)b * 8192 + t * 32 + d4];
  ushort4 o;
  o.x = f2bf(v.x); o.y = f2bf(v.y); o.z = f2bf(v.z); o.w = f2bf(v.w);
  xp[idx] = o;
}

// ---- pack [W;U] into per-j-block MFMA B-fragment images ----------------
__global__ __launch_bounds__(256) void pack_w_k(const float* __restrict__ W,
                                                const float* __restrict__ U,
                                                u16* __restrict__ wp){
  int idx = blockIdx.x * 256 + threadIdx.x;          // 163840 threads
  int j = idx / 5120; int rem = idx % 5120;
  int kcg = rem >> 8; int rem2 = rem & 255;
  int n = rem2 >> 6; int lane = rem2 & 63;
  int col  = n * Hq + j * 16 + (lane & 15);
  int krow = kcg * 32 + ((lane >> 4) * 8);
  u16 vals[8];
  #pragma unroll
  for (int jj = 0; jj < 8; ++jj){
    int k = krow + jj;
    float v = (k < Dq) ? W[(size_t)k * GH + col] : U[(size_t)(k - Dq) * GH + col];
    vals[jj] = f2bf(v);
  }
  ushort4* dst = (ushort4*)(wp + (size_t)j * 40960 + ((size_t)(kcg * 4 + n) * 64 + lane) * 8);
  dst[0] = make_ushort4(vals[0], vals[1], vals[2], vals[3]);
  dst[1] = make_ushort4(vals[4], vals[5], vals[6], vals[7]);
}

// ---- persistent LSTM recurrence ---------------------------------------
// grid 512. R8 MAP (same-row CU pairing): k = bx>>1, row i = k&15,
// col j = 2*(k>>4) + (bx&1).
//  * Row i's blocks have k = i + 16m -> XCD = k&7 = i&7 constant under
//    the pair model => the placement probe still verifies L2 sharing.
//  * CU pair (2k, 2k+1) = same row, cols (2jp, 2jp+1): identical h-tile
//    (64KB) and x-slice (16KB) reads -> second block hits L1.
// Everything else = R6/R7 (proven): flag-store barrier, shadow x-GEMM,
// hoisted inv_l1, fast/slow h exchange, wu kc0..3 in regs, WL kc4..15.
__global__ __launch_bounds__(256, 2) void lstm_k(
    const u16* __restrict__ xp, const u16* __restrict__ wp,
    const float* __restrict__ bias, u16* __restrict__ hb,
    u32* __restrict__ ctr)
{
  __shared__ u16 WL[24576];                 // U-part B-frags kc 4..15, 48 KB
  __shared__ int sbad, sres;
  const int bx = blockIdx.x;
  const int k  = bx >> 1;
  const int i  = k & 15;                    // row (XCD = i&7 under pair model)
  const int j  = ((k >> 4) << 1) | (bx & 1);// col 0..31
  const int tid = threadIdx.x;
  const int lane = tid & 63, wv = tid >> 6;
  const int l15 = lane & 15, quad = lane >> 4;
  const int koff = quad * 8;

  u32* tok   = ctr;                         // [512] placement tokens (b 0..2047)
  u32* pc1   = ctr + 528;                   // probe barrier 1 (b 2112)
  u32* pc2   = ctr + 544;                   // probe barrier 2 (b 2176)
  u32* bad   = ctr + 560;                   // global verdict (b 2240)
  u32* flg   = ctr + 1024;                  // step flags: (i*32+c)*16 u32
                                            // (64 B apart; b 4096..36863)

  // ---- placement probe ----
  u32 xcc = __builtin_amdgcn_s_getreg(63508) & 0xffu; // hwreg(HW_REG_XCC_ID=20,0,32)
  if (tid == 0){
    tok[bx] = (xcc << 16) | ((u32)(bx + 1) & 0xffffu);  // plain store -> local L2
    sbad = 0;
  }
  __syncthreads();                           // drains vmcnt; compiler barrier
  if (tid == 0) agent_bar(pc1, NROW * NCOL);
  __syncthreads();
  inv_l1();
  if (tid < NCOL){
    // row i, col c=tid was written by block pb = 2*(i + 16*(c>>1)) + (c&1);
    // plain load sees the correct xcc-tagged token only if that block
    // shares our L2.
    int pb = ((i + ((tid >> 1) << 4)) << 1) | (tid & 1);
    u32 v = tok[pb];
    u32 expect = (xcc << 16) | ((u32)(pb + 1) & 0xffffu);
    if (v != expect) atomicOr(&sbad, 1);
  }
  __syncthreads();
  if (tid == 0){
    if (sbad) __hip_atomic_fetch_or(bad, 1u, __ATOMIC_RELAXED, __HIP_MEMORY_SCOPE_AGENT);
    agent_bar(pc2, NROW * NCOL);             // all verdicts merged
    sres = (int)__hip_atomic_load(bad, __ATOMIC_RELAXED, __HIP_MEMORY_SCOPE_AGENT);
  }
  __syncthreads();
  const bool fast = (sres == 0);             // grid-uniform decision

  // x-part weights (K=0..127) -> registers: wx[kc][n]
  const u16* wj = wp + (size_t)j * 40960;
  bf16x8 wx[4][4];
  #pragma unroll
  for (int kc = 0; kc < 4; ++kc)
    #pragma unroll
    for (int n = 0; n < 4; ++n)
      wx[kc][n] = *(const bf16x8*)(wj + ((kc * 4 + n) * 64 + lane) * 8);

  // U-part weights kc 0..3 (K=128..255) -> persistent registers (64 VGPRs)
  bf16x8 wu[4][4];
  #pragma unroll
  for (int kc = 0; kc < 4; ++kc)
    #pragma unroll
    for (int n = 0; n < 4; ++n)
      wu[kc][n] = *(const bf16x8*)(wj + 8192 + ((kc * 4 + n) * 64 + lane) * 8);

  // U-part weights kc 4..15 (K=256..639) -> LDS (48 KB)
  {
    const uint4* src = (const uint4*)(wj + 16384);
    uint4* dst = (uint4*)WL;
    #pragma unroll
    for (int q = 0; q < 12; ++q) dst[tid + q * 256] = src[tid + q * 256];
  }
  __syncthreads();

  const int hc = j * 16 + l15;
  const float bi  = bias[hc];
  const float bf_ = bias[Hq + hc];
  const float bg  = bias[2 * Hq + hc];
  const float bo  = bias[3 * Hq + hc];
  const int row0 = i * MBr + wv * 16 + l15; // this wave's A-rows
  float cst[4] = {0.f, 0.f, 0.f, 0.f};

  u32* myflag   = flg + ((size_t)i * 32 + j) * 16;       // this block's slot
  u32* gatherp  = flg + ((size_t)i * 32 + (lane & 31)) * 16; // wave-gather addr

  // ---- x-part for t=0 (pre-loop) ----
  f32x4 acc[4];
  #pragma unroll
  for (int n = 0; n < 4; ++n) acc[n] = (f32x4){0.f, 0.f, 0.f, 0.f};
  {
    bf16x8 ax[4];
    #pragma unroll
    for (int kc = 0; kc < 4; ++kc)
      ax[kc] = *(const bf16x8*)(xp + (size_t)row0 * Dq + kc * 32 + koff);
    #pragma unroll
    for (int kc = 0; kc < 4; ++kc)
      #pragma unroll
      for (int n = 0; n < 4; ++n)
        acc[n] = __builtin_amdgcn_mfma_f32_16x16x32_bf16(ax[kc], wx[kc][n], acc[n], 0, 0, 0);
  }

  for (int t = 0; t < Tq; ++t){
    // acc already holds the x-part for step t (pre-loop or barrier shadow).

    // ---- K part 2: h_t (kc 0..15); kc<4 B from regs, kc>=4 from LDS ----
    if (t > 0){
      const u16* hcur = hb + (size_t)(t & 1) * (Bq * Hq);
      bf16x8 ah[16];
      if (fast){
        #pragma unroll
        for (int kc = 0; kc < 16; ++kc)      // plain dwordx4: L1/L2 hits
          ah[kc] = *(const bf16x8*)(hcur + (size_t)row0 * Hq + kc * 32 + koff);
      } else {
        #pragma unroll
        for (int kc = 0; kc < 16; ++kc)
          ah[kc] = ld_h16_agent(hcur + (size_t)row0 * Hq + kc * 32 + koff);
      }
      #pragma unroll
      for (int kc = 0; kc < 4; ++kc){        // register-B: no lgkmcnt dep
        #pragma unroll
        for (int n = 0; n < 4; ++n)
          acc[n] = __builtin_amdgcn_mfma_f32_16x16x32_bf16(ah[kc], wu[kc][n], acc[n], 0, 0, 0);
      }
      #pragma unroll
      for (int kc = 4; kc < 16; ++kc){
        #pragma unroll
        for (int n = 0; n < 4; ++n){
          bf16x8 bw = *(const bf16x8*)(WL + (((kc - 4) * 4 + n) * 64 + lane) * 8);
          acc[n] = __builtin_amdgcn_mfma_f32_16x16x32_bf16(ah[kc], bw, acc[n], 0, 0, 0);
        }
      }
    }

    // ---- gate epilogue; c in registers; h stores (mode-dependent) ----
    // C-layout: col = lane&15 (= h-col), row = quad*4 + reg  [m89/m91]
    u16* hn = hb + (size_t)((t + 1) & 1) * (Bq * Hq);
    #pragma unroll
    for (int r = 0; r < 4; ++r){
      float gi = acc[0][r] + bi;
      float gf = acc[1][r] + bf_;
      float gg = acc[2][r] + bg;
      float go = acc[3][r] + bo;
      float iv = sigmf_(gi), fv = sigmf_(gf);
      float gv = softplusf_(gg), ov = sigmf_(go);
      float cn = fv * cst[r] + iv * gv;
      cst[r] = cn;
      float hv = ov * softplusf_(cn);
      int row = i * MBr + wv * 16 + quad * 4 + r;
      u16* dst = hn + (size_t)row * Hq + hc;
      if (fast) *dst = f2bf(hv);            // plain store -> local L2
      else __hip_atomic_store(dst, f2bf(hv), __ATOMIC_RELAXED, __HIP_MEMORY_SCOPE_AGENT);
    }

    // ---- flag barrier with x-GEMM of t+1 in its shadow ----
    if (t + 1 < Tq){
      const u32 target = (u32)(t + 1);
      __syncthreads();                       // vmcnt(0): h stores in L2/L3
      if (tid == 0)                          // announce: ONE plain sc1 store
        __hip_atomic_store(myflag, target, __ATOMIC_RELAXED, __HIP_MEMORY_SCOPE_AGENT);

      // shadow work: x fragments + x-part MFMAs for step t+1 (h-independent)
      #pragma unroll
      for (int n = 0; n < 4; ++n) acc[n] = (f32x4){0.f, 0.f, 0.f, 0.f};
      {
        const u16* xt2 = xp + (size_t)(t + 1) * (Bq * Dq);
        bf16x8 ax[4];
        #pragma unroll
        for (int kc = 0; kc < 4; ++kc)
          ax[kc] = *(const bf16x8*)(xt2 + (size_t)row0 * Dq + kc * 32 + koff);
        #pragma unroll
        for (int kc = 0; kc < 4; ++kc)
          #pragma unroll
          for (int n = 0; n < 4; ++n)
            acc[n] = __builtin_amdgcn_mfma_f32_16x16x32_bf16(ax[kc], wx[kc][n], acc[n], 0, 0, 0);
      }

      inv_l1();                              // hoisted: drop stale h lines
                                             // BEFORE the poll; poll loads
                                             // are sc1 (bypass L1); no h
                                             // load until after the wait
      if (wv == 0){                          // wave 0 gathers the 32 flags
        for (int w = 0; w < POLL_CAP; ++w){
          u32 f = __hip_atomic_load(gatherp, __ATOMIC_RELAXED, __HIP_MEMORY_SCOPE_AGENT);
          if (__ballot(f >= target) == ~0ull) break;
          __builtin_amdgcn_s_sleep(1);
        }
      }
      __syncthreads();
    }
  }
}

// ---- final projection: mu, logvar, z ----------------------------------
__global__ __launch_bounds__(64) void proj_k(const u16* __restrict__ h0,
    const float* __restrict__ Wm, const float* __restrict__ bm,
    const float* __restrict__ Wv, const float* __restrict__ bv,
    const float* __restrict__ eps, float* __restrict__ out)
{
  __shared__ float hs[Hq];
  int b = blockIdx.x, lane = threadIdx.x;
  const u16* hr = h0 + (size_t)b * Hq;
  #pragma unroll
  for (int q = 0; q < 8; ++q) hs[lane * 8 + q] = bf2f(hr[lane * 8 + q]);
  __syncthreads();
  float am = 0.f, av = 0.f;
  #pragma unroll 8
  for (int k = 0; k < Hq; ++k){
    float h = hs[k];
    am = fmaf(h, Wm[(size_t)k * Zq + lane], am);
    av = fmaf(h, Wv[(size_t)k * Zq + lane], av);
  }
  float mu = am + bm[lane];
  float lv = av + bv[lane];
  float z  = mu + eps[(size_t)b * Zq + lane] * expf(0.5f * lv);
  size_t o = (size_t)b * Zq + lane;
  out[o]           = mu;
  out[65536 + o]   = lv;
  out[131072 + o]  = z;
}

extern "C" void kernel_launch(void* const* d_in, const int* in_sizes, int n_in,
                              void* d_out, int out_size, void* d_ws, size_t ws_size,
                              hipStream_t stream)
{
  const float* x   = (const float*)d_in[0];
  const float* eps = (const float*)d_in[1];
  const float* W   = (const float*)d_in[2];
  const float* U   = (const float*)d_in[3];
  const float* bb  = (const float*)d_in[4];
  const float* Wm  = (const float*)d_in[5];
  const float* bm  = (const float*)d_in[6];
  const float* Wv  = (const float*)d_in[7];
  const float* bv  = (const float*)d_in[8];

  char* ws = (char*)d_ws;
  u16* xp = (u16*)(ws + XP_OFF);
  u16* wp = (u16*)(ws + WP_OFF);
  u16* hb = (u16*)(ws + HB_OFF);
  u32* ctr = (u32*)(ws + CT_OFF);

  hipMemsetAsync(ctr, 0, 40960, stream);     // tokens + probe ctrs + flags
  pack_x_k<<<32768, 256, 0, stream>>>((const float4*)x, (ushort4*)xp);
  pack_w_k<<<640, 256, 0, stream>>>(W, U, wp);
  lstm_k<<<NROW * NCOL, 256, 0, stream>>>(xp, wp, bb, hb, ctr);
  // after 256 steps, h_last sits in parity (256 & 1) == 0
  proj_k<<<Bq, 64, 0, stream>>>(hb, Wm, bm, Wv, bv, eps, (float*)d_out);
}

// Round 9
// 2248.782 us; speedup vs baseline: 1.2725x; 1.2725x over previous
//
#include <hip/hip_runtime.h>

typedef unsigned short u16;
typedef unsigned int u32;
typedef unsigned long long u64;
typedef short bf16x8 __attribute__((ext_vector_type(8)));
typedef float f32x4 __attribute__((ext_vector_type(4)));

#define Bq 1024
#define Tq 256
#define Dq 128
#define Hq 512
#define GH 2048
#define Zq 64
#define NROW 16            // batch slices (rows)
#define NCOL 32            // h-col blocks per row
#define MBr 64             // batch rows per block

// workspace layout (bytes)
#define XP_OFF   0ull                      // x packed [T][B][D] bf16  : 67108864 B
#define WP_OFF   (XP_OFF + 67108864ull)    // W/U packed frags 32*81920: 2621440 B
#define HB_OFF   (WP_OFF + 2621440ull)     // h double buffer 2*[B][H] : 2097152 B
#define CT_OFF   (HB_OFF + 2097152ull)     // probe tokens + flags: 40960 B

#define POLL_CAP 65536                     // watchdog: never hang, fail loud

__device__ __forceinline__ u16 f2bf(float f){
  unsigned int u = __builtin_bit_cast(unsigned int, f);
  u += 0x7fffu + ((u >> 16) & 1u);          // RNE; inputs finite
  return (u16)(u >> 16);
}
__device__ __forceinline__ float bf2f(u16 v){
  unsigned int u = ((unsigned int)v) << 16;
  return __builtin_bit_cast(float, u);
}
__device__ __forceinline__ float sigmf_(float x){
  return 1.0f / (1.0f + __expf(-x));
}
__device__ __forceinline__ float softplusf_(float x){
  float r = __logf(1.0f + __expf(x));
  return (x > 20.0f) ? x : r;               // guard overflow: softplus(x)->x
}

// agent-coherent 16B load (sc1 path, reads coherence point) -- slow mode
__device__ __forceinline__ bf16x8 ld_h16_agent(const u16* p){
  union { u64 q[2]; bf16x8 v; } u;
  const u64* q = (const u64*)p;
  u.q[0] = __hip_atomic_load(q,     __ATOMIC_RELAXED, __HIP_MEMORY_SCOPE_AGENT);
  u.q[1] = __hip_atomic_load(q + 1, __ATOMIC_RELAXED, __HIP_MEMORY_SCOPE_AGENT);
  return u.v;
}
__device__ __forceinline__ void inv_l1(){
  asm volatile("buffer_inv sc0" ::: "memory");   // L1-only invalidate
}
// agent barrier pieces (PROVEN in R0; used for the one-time probe only).
// SYNC PROTOCOL LEDGER (hard-won):
//   R2: workgroup-scope atomics as cross-block barrier -> invisible.
//   R4: per-wave arrivals -> RMW serialization tripled step cost.
//   R5: inline-asm no-sc1 atomic -> container death.
//   R6: per-block monotonic FLAG STORES + wave-parallel sc1 gather: WORKS.
//   R7: anti-phase stagger: ~null (throughput-bound, not stall-phase).
// PLACEMENT LEDGER: R0 map (i=bx&15) PASSES the L2-sharing probe.
//   R1 map (XCD=bx&7 model) FAILED. R8 map (XCD=(bx>>1)&7 model) FAILED.
//   Dispatcher topology unknown; placement remaps are CLOSED. R0 map only.
// R9: register-residency fix. VGPR=120 proved wx+wu were never resident
//   (compiler reloads ~32 weight frags/wave/step from L2 on the critical
//   path). New budget: wu[8][4]=128 VGPR resident (critical path), wx
//   deliberately per-step-loaded in the poll shadow via opaque pointer,
//   WL shrinks to 8 kc = 32 KB (-25% LDS traffic).
__device__ __forceinline__ u32 bar_arrive(u32* c){
  return __hip_atomic_fetch_add(c, 1u, __ATOMIC_RELAXED, __HIP_MEMORY_SCOPE_AGENT);
}
__device__ __forceinline__ void bar_poll(u32* c, u32 target){
  for (int w = 0; w < POLL_CAP; ++w){
    if (__hip_atomic_load(c, __ATOMIC_RELAXED, __HIP_MEMORY_SCOPE_AGENT) >= target) break;
    __builtin_amdgcn_s_sleep(1);
  }
}
__device__ __forceinline__ void agent_bar(u32* c, u32 target){
  u32 old = bar_arrive(c);
  if (old + 1u >= target) return;            // last arriver: no poll
  bar_poll(c, target);
}

// ---- pack x [B,T,D] fp32 -> [T,B,D] bf16 -------------------------------
__global__ __launch_bounds__(256) void pack_x_k(const float4* __restrict__ x,
                                                ushort4* __restrict__ xp){
  int idx = blockIdx.x * 256 + threadIdx.x;          // 8,388,608 float4s
  int t = idx >> 15, rem = idx & 32767, b = rem >> 5, d4 = rem & 31;
  float4 v = x[(size_t)b * 8192 + t * 32 + d4];
  ushort4 o;
  o.x = f2bf(v.x); o.y = f2bf(v.y); o.z = f2bf(v.z); o.w = f2bf(v.w);
  xp[idx] = o;
}

// ---- pack [W;U] into per-j-block MFMA B-fragment images ----------------
__global__ __launch_bounds__(256) void pack_w_k(const float* __restrict__ W,
                                                const float* __restrict__ U,
                                                u16* __restrict__ wp){
  int idx = blockIdx.x * 256 + threadIdx.x;          // 163840 threads
  int j = idx / 5120; int rem = idx % 5120;
  int kcg = rem >> 8; int rem2 = rem & 255;
  int n = rem2 >> 6; int lane = rem2 & 63;
  int col  = n * Hq + j * 16 + (lane & 15);
  int krow = kcg * 32 + ((lane >> 4) * 8);
  u16 vals[8];
  #pragma unroll
  for (int jj = 0; jj < 8; ++jj){
    int k = krow + jj;
    float v = (k < Dq) ? W[(size_t)k * GH + col] : U[(size_t)(k - Dq) * GH + col];
    vals[jj] = f2bf(v);
  }
  ushort4* dst = (ushort4*)(wp + (size_t)j * 40960 + ((size_t)(kcg * 4 + n) * 64 + lane) * 8);
  dst[0] = make_ushort4(vals[0], vals[1], vals[2], vals[3]);
  dst[1] = make_ushort4(vals[4], vals[5], vals[6], vals[7]);
}

// ---- persistent LSTM recurrence ---------------------------------------
// grid 512: bx -> row i = bx&15, col j = bx>>4 (R0-proven map, PINNED).
// Flag-store barrier (R6), shadow x-GEMM in the poll window, hoisted
// inv_l1, fast/slow h exchange, anti-phase stagger (R7, harmless).
// R9 register plan (see ledger above): wu = U-kc 0..7 resident (128
// VGPR); WL = U-kc 8..15 (32 KB LDS); wx loaded per step inside the
// shadow through an OPAQUE pointer so LICM cannot hoist it back into
// residency (which would demote wu again, as R1/R3 showed).
__global__ __launch_bounds__(256, 2) void lstm_k(
    const u16* __restrict__ xp, const u16* __restrict__ wp,
    const float* __restrict__ bias, u16* __restrict__ hb,
    u32* __restrict__ ctr)
{
  __shared__ u16 WL[16384];                 // U-part B-frags kc 8..15, 32 KB
  __shared__ int sbad, sres;
  const int bx = blockIdx.x;
  const int i = bx & 15, j = bx >> 4;       // row, col
  const int tid = threadIdx.x;
  const int lane = tid & 63, wv = tid >> 6;
  const int l15 = lane & 15, quad = lane >> 4;
  const int koff = quad * 8;

  u32* tok   = ctr;                         // [512] placement tokens (b 0..2047)
  u32* pc1   = ctr + 528;                   // probe barrier 1 (b 2112)
  u32* pc2   = ctr + 544;                   // probe barrier 2 (b 2176)
  u32* bad   = ctr + 560;                   // global verdict (b 2240)
  u32* flg   = ctr + 1024;                  // step flags: (i*32+c)*16 u32
                                            // (64 B apart; b 4096..36863)

  // ---- placement probe (R0 formula, proven) ----
  u32 xcc = __builtin_amdgcn_s_getreg(63508) & 0xffu; // hwreg(HW_REG_XCC_ID=20,0,32)
  if (tid == 0){
    tok[bx] = (xcc << 16) | ((u32)(bx + 1) & 0xffffu);  // plain store -> local L2
    sbad = 0;
  }
  __syncthreads();                           // drains vmcnt; compiler barrier
  if (tid == 0) agent_bar(pc1, NROW * NCOL);
  __syncthreads();
  inv_l1();
  if (tid < NCOL){
    // row i, col tid was written by block bx' = tid*16 + i; plain load sees
    // the correct xcc-tagged token only if that block shares our L2.
    u32 v = tok[tid * 16 + i];
    u32 expect = (xcc << 16) | ((u32)(tid * 16 + i + 1) & 0xffffu);
    if (v != expect) atomicOr(&sbad, 1);
  }
  __syncthreads();
  if (tid == 0){
    if (sbad) __hip_atomic_fetch_or(bad, 1u, __ATOMIC_RELAXED, __HIP_MEMORY_SCOPE_AGENT);
    agent_bar(pc2, NROW * NCOL);             // all verdicts merged
    sres = (int)__hip_atomic_load(bad, __ATOMIC_RELAXED, __HIP_MEMORY_SCOPE_AGENT);
  }
  __syncthreads();
  const bool fast = (sres == 0);             // grid-uniform decision

  const u16* wj = wp + (size_t)j * 40960;

  // U-part weights kc 0..7 (K=128..383) -> persistent registers (128 VGPR)
  bf16x8 wu[8][4];
  #pragma unroll
  for (int kc = 0; kc < 8; ++kc)
    #pragma unroll
    for (int n = 0; n < 4; ++n)
      wu[kc][n] = *(const bf16x8*)(wj + 8192 + ((kc * 4 + n) * 64 + lane) * 8);

  // U-part weights kc 8..15 (K=384..639) -> LDS (32 KB)
  {
    const uint4* src = (const uint4*)(wj + 24576);
    uint4* dst = (uint4*)WL;
    #pragma unroll
    for (int q = 0; q < 8; ++q) dst[tid + q * 256] = src[tid + q * 256];
  }
  __syncthreads();

  // ---- anti-phase stagger for odd rows (R7; ~null but never harmful) ----
  if (i & 1){
    #pragma unroll 1
    for (int s = 0; s < 16; ++s) __builtin_amdgcn_s_sleep(8);
  }

  const int hc = j * 16 + l15;
  const float bi  = bias[hc];
  const float bf_ = bias[Hq + hc];
  const float bg  = bias[2 * Hq + hc];
  const float bo  = bias[3 * Hq + hc];
  const int row0 = i * MBr + wv * 16 + l15; // this wave's A-rows
  float cst[4] = {0.f, 0.f, 0.f, 0.f};

  u32* myflag   = flg + ((size_t)i * 32 + j) * 16;       // this block's slot
  u32* gatherp  = flg + ((size_t)i * 32 + (lane & 31)) * 16; // wave-gather addr

  // ---- x-part for t=0 (pre-loop); wx via opaque ptr (not resident) ----
  f32x4 acc[4];
  #pragma unroll
  for (int n = 0; n < 4; ++n) acc[n] = (f32x4){0.f, 0.f, 0.f, 0.f};
  {
    const u16* wjx = wj;
    asm volatile("" : "+v"(wjx));            // opaque: no LICM/residency
    bf16x8 ax[4];
    #pragma unroll
    for (int kc = 0; kc < 4; ++kc)
      ax[kc] = *(const bf16x8*)(xp + (size_t)row0 * Dq + kc * 32 + koff);
    #pragma unroll
    for (int kc = 0; kc < 4; ++kc)
      #pragma unroll
      for (int n = 0; n < 4; ++n){
        bf16x8 wf = *(const bf16x8*)(wjx + ((kc * 4 + n) * 64 + lane) * 8);
        acc[n] = __builtin_amdgcn_mfma_f32_16x16x32_bf16(ax[kc], wf, acc[n], 0, 0, 0);
      }
  }

  for (int t = 0; t < Tq; ++t){
    // acc already holds the x-part for step t (pre-loop or barrier shadow).

    // ---- K part 2: h_t (U-kc 0..15); kc<8 from wu regs, kc>=8 from LDS ----
    if (t > 0){
      const u16* hcur = hb + (size_t)(t & 1) * (Bq * Hq);
      bf16x8 ah[16];
      if (fast){
        #pragma unroll
        for (int kc = 0; kc < 16; ++kc)      // plain dwordx4: local-L2 hits
          ah[kc] = *(const bf16x8*)(hcur + (size_t)row0 * Hq + kc * 32 + koff);
      } else {
        #pragma unroll
        for (int kc = 0; kc < 16; ++kc)
          ah[kc] = ld_h16_agent(hcur + (size_t)row0 * Hq + kc * 32 + koff);
      }
      #pragma unroll
      for (int kc = 0; kc < 8; ++kc){        // register-B: no lgkmcnt dep
        #pragma unroll
        for (int n = 0; n < 4; ++n)
          acc[n] = __builtin_amdgcn_mfma_f32_16x16x32_bf16(ah[kc], wu[kc][n], acc[n], 0, 0, 0);
      }
      #pragma unroll
      for (int kc = 8; kc < 16; ++kc){
        #pragma unroll
        for (int n = 0; n < 4; ++n){
          bf16x8 bw = *(const bf16x8*)(WL + (((kc - 8) * 4 + n) * 64 + lane) * 8);
          acc[n] = __builtin_amdgcn_mfma_f32_16x16x32_bf16(ah[kc], bw, acc[n], 0, 0, 0);
        }
      }
    }

    // ---- gate epilogue; c in registers; h stores (mode-dependent) ----
    // C-layout: col = lane&15 (= h-col), row = quad*4 + reg  [m89/m91]
    u16* hn = hb + (size_t)((t + 1) & 1) * (Bq * Hq);
    #pragma unroll
    for (int r = 0; r < 4; ++r){
      float gi = acc[0][r] + bi;
      float gf = acc[1][r] + bf_;
      float gg = acc[2][r] + bg;
      float go = acc[3][r] + bo;
      float iv = sigmf_(gi), fv = sigmf_(gf);
      float gv = softplusf_(gg), ov = sigmf_(go);
      float cn = fv * cst[r] + iv * gv;
      cst[r] = cn;
      float hv = ov * softplusf_(cn);
      int row = i * MBr + wv * 16 + quad * 4 + r;
      u16* dst = hn + (size_t)row * Hq + hc;
      if (fast) *dst = f2bf(hv);            // plain store -> local L2
      else __hip_atomic_store(dst, f2bf(hv), __ATOMIC_RELAXED, __HIP_MEMORY_SCOPE_AGENT);
    }

    // ---- flag barrier with x-GEMM of t+1 in its shadow ----
    if (t + 1 < Tq){
      const u32 target = (u32)(t + 1);
      __syncthreads();                       // vmcnt(0): h stores in L2/L3
      if (tid == 0)                          // announce: ONE plain sc1 store
        __hip_atomic_store(myflag, target, __ATOMIC_RELAXED, __HIP_MEMORY_SCOPE_AGENT);

      // shadow work: x frags + W frags (opaque ptr) + x-part MFMAs for
      // step t+1 -- all h-independent, latency hidden by the poll wait.
      #pragma unroll
      for (int n = 0; n < 4; ++n) acc[n] = (f32x4){0.f, 0.f, 0.f, 0.f};
      {
        const u16* wjx = wj;
        asm volatile("" : "+v"(wjx));        // opaque: reload here, in the
                                             // latency-tolerant window
        const u16* xt2 = xp + (size_t)(t + 1) * (Bq * Dq);
        bf16x8 ax[4];
        #pragma unroll
        for (int kc = 0; kc < 4; ++kc)
          ax[kc] = *(const bf16x8*)(xt2 + (size_t)row0 * Dq + kc * 32 + koff);
        #pragma unroll
        for (int kc = 0; kc < 4; ++kc)
          #pragma unroll
          for (int n = 0; n < 4; ++n){
            bf16x8 wf = *(const bf16x8*)(wjx + ((kc * 4 + n) * 64 + lane) * 8);
            acc[n] = __builtin_amdgcn_mfma_f32_16x16x32_bf16(ax[kc], wf, acc[n], 0, 0, 0);
          }
      }

      inv_l1();                              // hoisted: drop stale h lines
                                             // BEFORE the poll; poll loads
                                             // are sc1 (bypass L1); no h
                                             // load until after the wait
      if (wv == 0){                          // wave 0 gathers the 32 flags
        for (int w = 0; w < POLL_CAP; ++w){
          u32 f = __hip_atomic_load(gatherp, __ATOMIC_RELAXED, __HIP_MEMORY_SCOPE_AGENT);
          if (__ballot(f >= target) == ~0ull) break;
          __builtin_amdgcn_s_sleep(1);
        }
      }
      __syncthreads();
    }
  }
}

// ---- final projection: mu, logvar, z ----------------------------------
__global__ __launch_bounds__(64) void proj_k(const u16* __restrict__ h0,
    const float* __restrict__ Wm, const float* __restrict__ bm,
    const float* __restrict__ Wv, const float* __restrict__ bv,
    const float* __restrict__ eps, float* __restrict__ out)
{
  __shared__ float hs[Hq];
  int b = blockIdx.x, lane = threadIdx.x;
  const u16* hr = h0 + (size_t)b * Hq;
  #pragma unroll
  for (int q = 0; q < 8; ++q) hs[lane * 8 + q] = bf2f(hr[lane * 8 + q]);
  __syncthreads();
  float am = 0.f, av = 0.f;
  #pragma unroll 8
  for (int k = 0; k < Hq; ++k){
    float h = hs[k];
    am = fmaf(h, Wm[(size_t)k * Zq + lane], am);
    av = fmaf(h, Wv[(size_t)k * Zq + lane], av);
  }
  float mu = am + bm[lane];
  float lv = av + bv[lane];
  float z  = mu + eps[(size_t)b * Zq + lane] * expf(0.5f * lv);
  size_t o = (size_t)b * Zq + lane;
  out[o]           = mu;
  out[65536 + o]   = lv;
  out[131072 + o]  = z;
}

extern "C" void kernel_launch(void* const* d_in, const int* in_sizes, int n_in,
                              void* d_out, int out_size, void* d_ws, size_t ws_size,
                              hipStream_t stream)
{
  const float* x   = (const float*)d_in[0];
  const float* eps = (const float*)d_in[1];
  const float* W   = (const float*)d_in[2];
  const float* U   = (const float*)d_in[3];
  const float* bb  = (const float*)d_in[4];
  const float* Wm  = (const float*)d_in[5];
  const float* bm  = (const float*)d_in[6];
  const float* Wv  = (const float*)d_in[7];
  const float* bv  = (const float*)d_in[8];

  char* ws = (char*)d_ws;
  u16* xp = (u16*)(ws + XP_OFF);
  u16* wp = (u16*)(ws + WP_OFF);
  u16* hb = (u16*)(ws + HB_OFF);
  u32* ctr = (u32*)(ws + CT_OFF);

  hipMemsetAsync(ctr, 0, 40960, stream);     // tokens + probe ctrs + flags
  pack_x_k<<<32768, 256, 0, stream>>>((const float4*)x, (ushort4*)xp);
  pack_w_k<<<640, 256, 0, stream>>>(W, U, wp);
  lstm_k<<<NROW * NCOL, 256, 0, stream>>>(xp, wp, bb, hb, ctr);
  // after 256 steps, h_last sits in parity (256 & 1) == 0
  proj_k<<<Bq, 64, 0, stream>>>(hb, Wm, bm, Wv, bv, eps, (float*)d_out);
}

// Round 11
// 1855.374 us; speedup vs baseline: 1.5423x; 1.2120x over previous
//
#include <hip/hip_runtime.h>

typedef unsigned short u16;
typedef unsigned int u32;
typedef unsigned long long u64;
typedef short bf16x8 __attribute__((ext_vector_type(8)));
typedef float f32x4 __attribute__((ext_vector_type(4)));

#define Bq 1024
#define Tq 256
#define Dq 128
#define Hq 512
#define GH 2048
#define Zq 64
#define NROW 16            // batch slices (rows)
#define NCOL 32            // h-col blocks per row
#define MBr 64             // batch rows per block

// workspace layout (bytes)
#define XP_OFF   0ull                      // x packed [T][B][D] bf16  : 67108864 B
#define WP_OFF   (XP_OFF + 67108864ull)    // W/U packed frags 32*81920: 2621440 B
#define HB_OFF   (WP_OFF + 2621440ull)     // h double buffer 2*[B][H] : 2097152 B
#define CT_OFF   (HB_OFF + 2097152ull)     // probe tokens + flags: 40960 B

#define POLL_CAP 65536                     // watchdog: never hang, fail loud

__device__ __forceinline__ u16 f2bf(float f){
  unsigned int u = __builtin_bit_cast(unsigned int, f);
  u += 0x7fffu + ((u >> 16) & 1u);          // RNE; inputs finite
  return (u16)(u >> 16);
}
__device__ __forceinline__ float bf2f(u16 v){
  unsigned int u = ((unsigned int)v) << 16;
  return __builtin_bit_cast(float, u);
}
__device__ __forceinline__ float sigmf_(float x){
  return 1.0f / (1.0f + __expf(-x));
}
__device__ __forceinline__ float softplusf_(float x){
  float r = __logf(1.0f + __expf(x));
  return (x > 20.0f) ? x : r;               // guard overflow: softplus(x)->x
}

// agent-coherent 16B load (sc1 path, reads coherence point) -- slow mode
__device__ __forceinline__ bf16x8 ld_h16_agent(const u16* p){
  union { u64 q[2]; bf16x8 v; } u;
  const u64* q = (const u64*)p;
  u.q[0] = __hip_atomic_load(q,     __ATOMIC_RELAXED, __HIP_MEMORY_SCOPE_AGENT);
  u.q[1] = __hip_atomic_load(q + 1, __ATOMIC_RELAXED, __HIP_MEMORY_SCOPE_AGENT);
  return u.v;
}
__device__ __forceinline__ void inv_l1(){
  asm volatile("buffer_inv sc0" ::: "memory");   // L1-only invalidate (probe only)
}
// SYNC PROTOCOL LEDGER (hard-won):
//   R2: workgroup-scope atomics as cross-block barrier -> invisible.
//   R4: per-wave arrivals -> RMW serialization tripled step cost.
//   R5: inline-asm no-sc1 ATOMIC -> container death.
//   R6: per-block monotonic FLAG STORES + wave-parallel sc1 gather: WORKS.
//   R7: anti-phase stagger: ~null. Kept (harmless).
//   R10: inline-asm VMEM loads -> container death. INLINE-ASM VMEM CLOSED:
//        all memory ops must be compiler-lowered builtins/intrinsics.
// PLACEMENT LEDGER: R0 map (i=bx&15) PASSES the L2-sharing probe.
//   R1 and R8 remaps both FAILED the probe. Placement remaps CLOSED.
// REGISTER LEDGER: compiler caps at ~128 VGPR here; forcing more weight
//   residency spills to scratch (R9: +27MB writes, +380us). CLOSED.
// R11: delete per-step inv_l1; fast-mode h loads use
//   __builtin_nontemporal_load (NT bit: no L1 allocation, compiler-
//   lowered, NO inline asm). h lines then never enter L1 -> no stale-L1
//   hazard. Failure mode if NT semantics differ: absmax fail (benign).
__device__ __forceinline__ u32 bar_arrive(u32* c){
  return __hip_atomic_fetch_add(c, 1u, __ATOMIC_RELAXED, __HIP_MEMORY_SCOPE_AGENT);
}
__device__ __forceinline__ void bar_poll(u32* c, u32 target){
  for (int w = 0; w < POLL_CAP; ++w){
    if (__hip_atomic_load(c, __ATOMIC_RELAXED, __HIP_MEMORY_SCOPE_AGENT) >= target) break;
    __builtin_amdgcn_s_sleep(1);
  }
}
__device__ __forceinline__ void agent_bar(u32* c, u32 target){
  u32 old = bar_arrive(c);
  if (old + 1u >= target) return;            // last arriver: no poll
  bar_poll(c, target);
}

// ---- pack x [B,T,D] fp32 -> [T,B,D] bf16 -------------------------------
__global__ __launch_bounds__(256) void pack_x_k(const float4* __restrict__ x,
                                                ushort4* __restrict__ xp){
  int idx = blockIdx.x * 256 + threadIdx.x;          // 8,388,608 float4s
  int t = idx >> 15, rem = idx & 32767, b = rem >> 5, d4 = rem & 31;
  float4 v = x[(size_t)b * 8192 + t * 32 + d4];
  ushort4 o;
  o.x = f2bf(v.x); o.y = f2bf(v.y); o.z = f2bf(v.z); o.w = f2bf(v.w);
  xp[idx] = o;
}

// ---- pack [W;U] into per-j-block MFMA B-fragment images ----------------
__global__ __launch_bounds__(256) void pack_w_k(const float* __restrict__ W,
                                                const float* __restrict__ U,
                                                u16* __restrict__ wp){
  int idx = blockIdx.x * 256 + threadIdx.x;          // 163840 threads
  int j = idx / 5120; int rem = idx % 5120;
  int kcg = rem >> 8; int rem2 = rem & 255;
  int n = rem2 >> 6; int lane = rem2 & 63;
  int col  = n * Hq + j * 16 + (lane & 15);
  int krow = kcg * 32 + ((lane >> 4) * 8);
  u16 vals[8];
  #pragma unroll
  for (int jj = 0; jj < 8; ++jj){
    int k = krow + jj;
    float v = (k < Dq) ? W[(size_t)k * GH + col] : U[(size_t)(k - Dq) * GH + col];
    vals[jj] = f2bf(v);
  }
  ushort4* dst = (ushort4*)(wp + (size_t)j * 40960 + ((size_t)(kcg * 4 + n) * 64 + lane) * 8);
  dst[0] = make_ushort4(vals[0], vals[1], vals[2], vals[3]);
  dst[1] = make_ushort4(vals[4], vals[5], vals[6], vals[7]);
}

// ---- persistent LSTM recurrence ---------------------------------------
// grid 512: bx -> row i = bx&15, col j = bx>>4 (R0-proven map, PINNED).
// Structure = R7 (proven 1743us) with ONE change: fast-mode h loads are
// __builtin_nontemporal_load (NT: no L1 allocation) and the per-step
// inv_l1 is DELETED. h lines can never be in L1 (stores are write-
// through; only h loads are NT; co-resident block's h rows disjoint),
// so post-barrier h reads are L2-coherent without any flush, and
// wp/bias L1 lines survive all 255 steps. Flag barrier (R6), shadow
// x-GEMM, wu kc0..3 regs, WL kc4..15 (48KB), stagger (R7) unchanged.
__global__ __launch_bounds__(256, 2) void lstm_k(
    const u16* __restrict__ xp, const u16* __restrict__ wp,
    const float* __restrict__ bias, u16* __restrict__ hb,
    u32* __restrict__ ctr)
{
  __shared__ u16 WL[24576];                 // U-part B-frags kc 4..15, 48 KB
  __shared__ int sbad, sres;
  const int bx = blockIdx.x;
  const int i = bx & 15, j = bx >> 4;       // row, col
  const int tid = threadIdx.x;
  const int lane = tid & 63, wv = tid >> 6;
  const int l15 = lane & 15, quad = lane >> 4;
  const int koff = quad * 8;

  u32* tok   = ctr;                         // [512] placement tokens (b 0..2047)
  u32* pc1   = ctr + 528;                   // probe barrier 1 (b 2112)
  u32* pc2   = ctr + 544;                   // probe barrier 2 (b 2176)
  u32* bad   = ctr + 560;                   // global verdict (b 2240)
  u32* flg   = ctr + 1024;                  // step flags: (i*32+c)*16 u32
                                            // (64 B apart; b 4096..36863)

  // ---- placement probe (R0 formula, proven) ----
  u32 xcc = __builtin_amdgcn_s_getreg(63508) & 0xffu; // hwreg(HW_REG_XCC_ID=20,0,32)
  if (tid == 0){
    tok[bx] = (xcc << 16) | ((u32)(bx + 1) & 0xffffu);  // plain store -> local L2
    sbad = 0;
  }
  __syncthreads();                           // drains vmcnt; compiler barrier
  if (tid == 0) agent_bar(pc1, NROW * NCOL);
  __syncthreads();
  inv_l1();                                  // one-time: drop pre-probe lines
  if (tid < NCOL){
    // row i, col tid was written by block bx' = tid*16 + i; plain load sees
    // the correct xcc-tagged token only if that block shares our L2.
    u32 v = tok[tid * 16 + i];
    u32 expect = (xcc << 16) | ((u32)(tid * 16 + i + 1) & 0xffffu);
    if (v != expect) atomicOr(&sbad, 1);
  }
  __syncthreads();
  if (tid == 0){
    if (sbad) __hip_atomic_fetch_or(bad, 1u, __ATOMIC_RELAXED, __HIP_MEMORY_SCOPE_AGENT);
    agent_bar(pc2, NROW * NCOL);             // all verdicts merged
    sres = (int)__hip_atomic_load(bad, __ATOMIC_RELAXED, __HIP_MEMORY_SCOPE_AGENT);
  }
  __syncthreads();
  const bool fast = (sres == 0);             // grid-uniform decision

  // x-part weights (K=0..127) -> registers: wx[kc][n]
  const u16* wj = wp + (size_t)j * 40960;
  bf16x8 wx[4][4];
  #pragma unroll
  for (int kc = 0; kc < 4; ++kc)
    #pragma unroll
    for (int n = 0; n < 4; ++n)
      wx[kc][n] = *(const bf16x8*)(wj + ((kc * 4 + n) * 64 + lane) * 8);

  // U-part weights kc 0..3 (K=128..255) -> persistent registers (64 VGPRs)
  bf16x8 wu[4][4];
  #pragma unroll
  for (int kc = 0; kc < 4; ++kc)
    #pragma unroll
    for (int n = 0; n < 4; ++n)
      wu[kc][n] = *(const bf16x8*)(wj + 8192 + ((kc * 4 + n) * 64 + lane) * 8);

  // U-part weights kc 4..15 (K=256..639) -> LDS (48 KB)
  {
    const uint4* src = (const uint4*)(wj + 16384);
    uint4* dst = (uint4*)WL;
    #pragma unroll
    for (int q = 0; q < 12; ++q) dst[tid + q * 256] = src[tid + q * 256];
  }
  __syncthreads();

  // ---- anti-phase stagger for odd rows (R7; ~null but never harmful) ----
  if (i & 1){
    #pragma unroll 1
    for (int s = 0; s < 16; ++s) __builtin_amdgcn_s_sleep(8);
  }

  const int hc = j * 16 + l15;
  const float bi  = bias[hc];
  const float bf_ = bias[Hq + hc];
  const float bg  = bias[2 * Hq + hc];
  const float bo  = bias[3 * Hq + hc];
  const int row0 = i * MBr + wv * 16 + l15; // this wave's A-rows
  float cst[4] = {0.f, 0.f, 0.f, 0.f};

  u32* myflag   = flg + ((size_t)i * 32 + j) * 16;       // this block's slot
  u32* gatherp  = flg + ((size_t)i * 32 + (lane & 31)) * 16; // wave-gather addr

  // ---- x-part for t=0 (pre-loop) ----
  f32x4 acc[4];
  #pragma unroll
  for (int n = 0; n < 4; ++n) acc[n] = (f32x4){0.f, 0.f, 0.f, 0.f};
  {
    bf16x8 ax[4];
    #pragma unroll
    for (int kc = 0; kc < 4; ++kc)
      ax[kc] = *(const bf16x8*)(xp + (size_t)row0 * Dq + kc * 32 + koff);
    #pragma unroll
    for (int kc = 0; kc < 4; ++kc)
      #pragma unroll
      for (int n = 0; n < 4; ++n)
        acc[n] = __builtin_amdgcn_mfma_f32_16x16x32_bf16(ax[kc], wx[kc][n], acc[n], 0, 0, 0);
  }

  for (int t = 0; t < Tq; ++t){
    // acc already holds the x-part for step t (pre-loop or barrier shadow).

    // ---- K part 2: h_t (kc 0..15); kc<4 B from regs, kc>=4 from LDS ----
    if (t > 0){
      const u16* hcur = hb + (size_t)(t & 1) * (Bq * Hq);
      bf16x8 ah[16];
      if (fast){
        // NT loads: no L1 allocation -> always L2-fresh, no flush needed.
        #pragma unroll
        for (int kc = 0; kc < 16; ++kc)
          ah[kc] = __builtin_nontemporal_load(
              (const bf16x8*)(hcur + (size_t)row0 * Hq + kc * 32 + koff));
      } else {
        #pragma unroll
        for (int kc = 0; kc < 16; ++kc)
          ah[kc] = ld_h16_agent(hcur + (size_t)row0 * Hq + kc * 32 + koff);
      }
      #pragma unroll
      for (int kc = 0; kc < 4; ++kc){        // register-B: no lgkmcnt dep
        #pragma unroll
        for (int n = 0; n < 4; ++n)
          acc[n] = __builtin_amdgcn_mfma_f32_16x16x32_bf16(ah[kc], wu[kc][n], acc[n], 0, 0, 0);
      }
      #pragma unroll
      for (int kc = 4; kc < 16; ++kc){
        #pragma unroll
        for (int n = 0; n < 4; ++n){
          bf16x8 bw = *(const bf16x8*)(WL + (((kc - 4) * 4 + n) * 64 + lane) * 8);
          acc[n] = __builtin_amdgcn_mfma_f32_16x16x32_bf16(ah[kc], bw, acc[n], 0, 0, 0);
        }
      }
    }

    // ---- gate epilogue; c in registers; h stores (mode-dependent) ----
    // C-layout: col = lane&15 (= h-col), row = quad*4 + reg  [m89/m91]
    u16* hn = hb + (size_t)((t + 1) & 1) * (Bq * Hq);
    #pragma unroll
    for (int r = 0; r < 4; ++r){
      float gi = acc[0][r] + bi;
      float gf = acc[1][r] + bf_;
      float gg = acc[2][r] + bg;
      float go = acc[3][r] + bo;
      float iv = sigmf_(gi), fv = sigmf_(gf);
      float gv = softplusf_(gg), ov = sigmf_(go);
      float cn = fv * cst[r] + iv * gv;
      cst[r] = cn;
      float hv = ov * softplusf_(cn);
      int row = i * MBr + wv * 16 + quad * 4 + r;
      u16* dst = hn + (size_t)row * Hq + hc;
      if (fast) *dst = f2bf(hv);            // plain store -> local L2
                                            // (write-through: L1 never
                                            // holds h lines)
      else __hip_atomic_store(dst, f2bf(hv), __ATOMIC_RELAXED, __HIP_MEMORY_SCOPE_AGENT);
    }

    // ---- flag barrier with x-GEMM of t+1 in its shadow ----
    if (t + 1 < Tq){
      const u32 target = (u32)(t + 1);
      __syncthreads();                       // vmcnt(0): h stores in L2/L3
      if (tid == 0)                          // announce: ONE plain sc1 store
        __hip_atomic_store(myflag, target, __ATOMIC_RELAXED, __HIP_MEMORY_SCOPE_AGENT);

      // shadow work: x fragments + x-part MFMAs for step t+1 (h-independent)
      #pragma unroll
      for (int n = 0; n < 4; ++n) acc[n] = (f32x4){0.f, 0.f, 0.f, 0.f};
      {
        const u16* xt2 = xp + (size_t)(t + 1) * (Bq * Dq);
        bf16x8 ax[4];
        #pragma unroll
        for (int kc = 0; kc < 4; ++kc)
          ax[kc] = *(const bf16x8*)(xt2 + (size_t)row0 * Dq + kc * 32 + koff);
        #pragma unroll
        for (int kc = 0; kc < 4; ++kc)
          #pragma unroll
          for (int n = 0; n < 4; ++n)
            acc[n] = __builtin_amdgcn_mfma_f32_16x16x32_bf16(ax[kc], wx[kc][n], acc[n], 0, 0, 0);
      }

      // (no per-step inv_l1 -- R11: h loads are NT, never in L1)
      if (wv == 0){                          // wave 0 gathers the 32 flags
        for (int w = 0; w < POLL_CAP; ++w){
          u32 f = __hip_atomic_load(gatherp, __ATOMIC_RELAXED, __HIP_MEMORY_SCOPE_AGENT);
          if (__ballot(f >= target) == ~0ull) break;
          __builtin_amdgcn_s_sleep(1);
        }
      }
      __syncthreads();
    }
  }
}

// ---- final projection: mu, logvar, z ----------------------------------
__global__ __launch_bounds__(64) void proj_k(const u16* __restrict__ h0,
    const float* __restrict__ Wm, const float* __restrict__ bm,
    const float* __restrict__ Wv, const float* __restrict__ bv,
    const float* __restrict__ eps, float* __restrict__ out)
{
  __shared__ float hs[Hq];
  int b = blockIdx.x, lane = threadIdx.x;
  const u16* hr = h0 + (size_t)b * Hq;
  #pragma unroll
  for (int q = 0; q < 8; ++q) hs[lane * 8 + q] = bf2f(hr[lane * 8 + q]);
  __syncthreads();
  float am = 0.f, av = 0.f;
  #pragma unroll 8
  for (int k = 0; k < Hq; ++k){
    float h = hs[k];
    am = fmaf(h, Wm[(size_t)k * Zq + lane], am);
    av = fmaf(h, Wv[(size_t)k * Zq + lane], av);
  }
  float mu = am + bm[lane];
  float lv = av + bv[lane];
  float z  = mu + eps[(size_t)b * Zq + lane] * expf(0.5f * lv);
  size_t o = (size_t)b * Zq + lane;
  out[o]           = mu;
  out[65536 + o]   = lv;
  out[131072 + o]  = z;
}

extern "C" void kernel_launch(void* const* d_in, const int* in_sizes, int n_in,
                              void* d_out, int out_size, void* d_ws, size_t ws_size,
                              hipStream_t stream)
{
  const float* x   = (const float*)d_in[0];
  const float* eps = (const float*)d_in[1];
  const float* W   = (const float*)d_in[2];
  const float* U   = (const float*)d_in[3];
  const float* bb  = (const float*)d_in[4];
  const float* Wm  = (const float*)d_in[5];
  const float* bm  = (const float*)d_in[6];
  const float* Wv  = (const float*)d_in[7];
  const float* bv  = (const float*)d_in[8];

  char* ws = (char*)d_ws;
  u16* xp = (u16*)(ws + XP_OFF);
  u16* wp = (u16*)(ws + WP_OFF);
  u16* hb = (u16*)(ws + HB_OFF);
  u32* ctr = (u32*)(ws + CT_OFF);

  hipMemsetAsync(ctr, 0, 40960, stream);     // tokens + probe ctrs + flags
  pack_x_k<<<32768, 256, 0, stream>>>((const float4*)x, (ushort4*)xp);
  pack_w_k<<<640, 256, 0, stream>>>(W, U, wp);
  lstm_k<<<NROW * NCOL, 256, 0, stream>>>(xp, wp, bb, hb, ctr);
  // after 256 steps, h_last sits in parity (256 & 1) == 0
  proj_k<<<Bq, 64, 0, stream>>>(hb, Wm, bm, Wv, bv, eps, (float*)d_out);
}